// Round 7
// baseline (188.794 us; speedup 1.0000x reference)
//
#include <hip/hip_runtime.h>
#include <hip/hip_bf16.h>

// A=8 agents, B=64 envs, S=1024 seq, H=128 hidden.
#define AN 8
#define BN 64
#define SN 1024
#define HN 128

typedef __attribute__((ext_vector_type(8))) short bf16x8;
typedef __attribute__((ext_vector_type(4))) float f32x4;

__device__ __forceinline__ unsigned short f2bf(float f) {
    unsigned u = __builtin_bit_cast(unsigned, f);
    return (unsigned short)((u + 0x7fffu + ((u >> 16) & 1u)) >> 16);  // RNE
}

// Pinned global load: volatile asm, early-clobber dst, immediate byte offset.
#define GLD4(dst, ptr, off)                                                    \
    asm volatile("global_load_dwordx4 %0, %1, off offset:" #off                \
                 : "=&v"(dst) : "v"(ptr) : "memory")

#define WAITV_(n) asm volatile("s_waitcnt vmcnt(" #n ")" ::: "memory")
#define WAITV(n) WAITV_(n)
#define SCHED0() __builtin_amdgcn_sched_barrier(0)

// ---- pack kernel: W -> bf16 MFMA fragments + bias into d_ws (verified R4/R6) ----
__global__ void pack_w(const float* __restrict__ W, const float* __restrict__ bias,
                       void* __restrict__ ws) {
    bf16x8* frag = (bf16x8*)ws;
    float*  bws  = (float*)((char*)ws + 2048 * 16);
    const int tid = threadIdx.x;
    for (int e = tid; e < 2048; e += 256) {
        int l  = e & 63;
        int ks = (e >> 6) & 3;
        int nt = e >> 8;
        int col = 16 * nt + (l & 15);
        int k0  = 32 * ks + 8 * (l >> 4);
        const float* wp = W + col * HN + k0;
        float4 w0 = *(const float4*)(wp);
        float4 w1 = *(const float4*)(wp + 4);
        bf16x8 f;
        f[0] = f2bf(w0.x); f[1] = f2bf(w0.y); f[2] = f2bf(w0.z); f[3] = f2bf(w0.w);
        f[4] = f2bf(w1.x); f[5] = f2bf(w1.y); f[6] = f2bf(w1.z); f[7] = f2bf(w1.w);
        frag[e] = f;
    }
    if (tid < HN) bws[tid] = bias[tid];
}

// Issue strip NEXTI's 8 rnn loads (pinned) into register buffer BUF.
#define RNPF(NEXTI, BUF) do {                                                  \
    const int srn_ = ((sblk0 + (NEXTI)) << 4) + rr;                            \
    const float* rp_ = rnn + ((size_t)srn_ * BN + b) * (AN * HN)               \
                           + a * HN + 8 * kg;                                  \
    GLD4(BUF[0], rp_, 0);   GLD4(BUF[1], rp_, 16);                             \
    GLD4(BUF[2], rp_, 128); GLD4(BUF[3], rp_, 144);                            \
    GLD4(BUF[4], rp_, 256); GLD4(BUF[5], rp_, 272);                            \
    GLD4(BUF[6], rp_, 384); GLD4(BUF[7], rp_, 400);                            \
} while (0)

// Process strip I from CUR. PF issues next strip's rnn. W1/W2: vmcnt literals.
#define BODY(I, CUR, PF, W1, W2) do {                                          \
    const int src_ = ((sblk0 + (I)) << 4) + rr;                                \
    const size_t ob_ = obsbase + (size_t)src_ * HN + 4 * kg;                   \
    const float* op_ = obs + ob_;                                              \
    float4 o0_, o1_, o2_, o3_, o4_, o5_, o6_, o7_;                             \
    GLD4(o0_, op_, 0);   GLD4(o1_, op_, 64);  GLD4(o2_, op_, 128);             \
    GLD4(o3_, op_, 192); GLD4(o4_, op_, 256); GLD4(o5_, op_, 320);             \
    GLD4(o6_, op_, 384); GLD4(o7_, op_, 448);                                  \
    PF;                                                                        \
    WAITV(W1); SCHED0();                                                       \
    const float sc_ = scales[I];                                               \
    bf16x8 mb_[4];                                                             \
    _Pragma("unroll")                                                          \
    for (int ks_ = 0; ks_ < 4; ++ks_) {                                        \
        float4 lo_ = CUR[2 * ks_], hi_ = CUR[2 * ks_ + 1];                     \
        mb_[ks_][0] = f2bf(lo_.x * sc_); mb_[ks_][1] = f2bf(lo_.y * sc_);      \
        mb_[ks_][2] = f2bf(lo_.z * sc_); mb_[ks_][3] = f2bf(lo_.w * sc_);      \
        mb_[ks_][4] = f2bf(hi_.x * sc_); mb_[ks_][5] = f2bf(hi_.y * sc_);      \
        mb_[ks_][6] = f2bf(hi_.z * sc_); mb_[ks_][7] = f2bf(hi_.w * sc_);      \
    }                                                                          \
    f32x4 acc_[8];                                                             \
    _Pragma("unroll")                                                          \
    for (int nt_ = 0; nt_ < 8; ++nt_) acc_[nt_] = (f32x4){0.f, 0.f, 0.f, 0.f}; \
    _Pragma("unroll")                                                          \
    for (int ks_ = 0; ks_ < 4; ++ks_) {                                        \
        _Pragma("unroll")                                                      \
        for (int nt_ = 0; nt_ < 8; ++nt_)                                      \
            acc_[nt_] = __builtin_amdgcn_mfma_f32_16x16x32_bf16(               \
                Wfrag[nt_][ks_][lane], mb_[ks_], acc_[nt_], 0, 0, 0);          \
    }                                                                          \
    WAITV(W2); SCHED0();                                                       \
    float4 obv_[8] = {o0_, o1_, o2_, o3_, o4_, o5_, o6_, o7_};                 \
    _Pragma("unroll")                                                          \
    for (int nt_ = 0; nt_ < 8; ++nt_) {                                        \
        float4 bi_ = *(const float4*)&bias_lds[16 * nt_ + 4 * kg];             \
        float4 r_;                                                             \
        r_.x = acc_[nt_][0] + bi_.x + obv_[nt_].x;                             \
        r_.y = acc_[nt_][1] + bi_.y + obv_[nt_].y;                             \
        r_.z = acc_[nt_][2] + bi_.z + obv_[nt_].z;                             \
        r_.w = acc_[nt_][3] + bi_.w + obv_[nt_].w;                             \
        *(float4*)(out + ob_ + 16 * nt_) = r_;                                 \
    }                                                                          \
} while (0)

__global__ __launch_bounds__(256) void commnet_main(
    const float* __restrict__ obs,   // (A*B, S, H)
    const float* __restrict__ rnn,   // (S, B, A, H)
    const int*   __restrict__ alive, // (A, B, S, 1)
    const void*  __restrict__ ws,    // packed W frags + bias
    float* __restrict__ out)         // (A*B, S, H)
{
    __shared__ bf16x8 Wfrag[8][4][64];   // 32 KiB
    __shared__ float  bias_lds[HN];

    const int tid  = threadIdx.x;
    const int lane = tid & 63;
    const int wv   = tid >> 6;      // 0..3 — waves fully independent
    const int rr   = lane & 15;     // strip row (s offset) / D row
    const int kg   = lane >> 4;     // k-group / out col-group

    // Stage W fragments + bias into LDS (once; only barrier in the kernel).
    {
        const bf16x8* wsfrag = (const bf16x8*)ws;
        const float*  bws    = (const float*)((const char*)ws + 2048 * 16);
        bf16x8* wflat = &Wfrag[0][0][0];
        for (int e = tid; e < 2048; e += 256) wflat[e] = wsfrag[e];
        if (tid < HN) bias_lds[tid] = bws[tid];
    }
    __syncthreads();

    // Wave -> 4 consecutive strips of one (a,b).
    const int wave_id = blockIdx.x * 4 + wv;
    const int strip0  = wave_id * 4;
    const int ab      = strip0 >> 6;
    const int sblk0   = strip0 & 63;
    const int a       = ab >> 6;
    const int b       = ab & 63;
    const size_t obsbase = (size_t)(a * BN + b) * (SN * HN);

    // alive scales for the 4 strips (plain loads; drained before asm region)
    float scales[4];
#pragma unroll
    for (int i = 0; i < 4; ++i) {
        const int s_r = ((sblk0 + i) << 4) + rr;
        int asum = 0, mya = 0;
#pragma unroll
        for (int a2 = 0; a2 < AN; ++a2) {
            int v = alive[(a2 * BN + b) * SN + s_r];
            asum += v;
            if (a2 == a) mya = v;
        }
        scales[i] = mya ? 1.0f / (float)(asum < 1 ? 1 : asum) : 0.0f;
    }

    // Pinned pipeline. Queue math (per wave, in-order retirement):
    //   prologue: rnn(0)x8
    //   iter i:   obs(i)x8, rnn(i+1)x8, wait rnn(i) -> W1, MFMA,
    //             wait obs(i) -> W2, stores(i)x8
    // W1 = younger-than-rnn(i); W2 = younger-than-obs(i).
    float4 rnA[8], rnB[8];
    RNPF(0, rnA);
    BODY(0, rnA, RNPF(1, rnB), 16, 8);
    BODY(1, rnB, RNPF(2, rnA), 24, 8);
    BODY(2, rnA, RNPF(3, rnB), 24, 8);
    BODY(3, rnB, (void)0,      16, 0);
}

extern "C" void kernel_launch(void* const* d_in, const int* in_sizes, int n_in,
                              void* d_out, int out_size, void* d_ws, size_t ws_size,
                              hipStream_t stream) {
    const float* obs   = (const float*)d_in[0];
    const float* rnn   = (const float*)d_in[1];
    const int*   alive = (const int*)d_in[2];
    const float* W     = (const float*)d_in[3];
    const float* bias  = (const float*)d_in[4];
    float* out = (float*)d_out;
    (void)in_sizes; (void)n_in; (void)ws_size; (void)out_size;

    pack_w<<<1, 256, 0, stream>>>(W, bias, d_ws);
    commnet_main<<<2048, 256, 0, stream>>>(obs, rnn, alive, d_ws, out);
}

// Round 8
// 146.139 us; speedup vs baseline: 1.2919x; 1.2919x over previous
//
#include <hip/hip_runtime.h>
#include <hip/hip_bf16.h>

// Problem constants: A=8 agents, B=64 envs, S=1024 seq, H=128 hidden.
#define AN 8
#define BN 64
#define SN 1024
#define HN 128
// rows M = A*B*S = 524288, strips of 16 rows = 32768 strips
#define NSTRIPS ((AN * BN * SN) / 16)

typedef __attribute__((ext_vector_type(8))) short bf16x8;
typedef __attribute__((ext_vector_type(4))) float f32x4;

__device__ __forceinline__ short f2bf(float f) {
    unsigned u = __builtin_bit_cast(unsigned, f);
    // round-to-nearest-even to bf16
    unsigned r = (u + 0x7fffu + ((u >> 16) & 1u)) >> 16;
    return (short)r;
}

__global__ __launch_bounds__(256) void commnet_fused(
    const float* __restrict__ obs,   // (A*B, S, H)
    const float* __restrict__ rnn,   // (S, B, A, H)
    const int*   __restrict__ alive, // (A, B, S, 1)
    const float* __restrict__ W,     // (H, H) [out, in]
    const float* __restrict__ bias,  // (H,)
    float* __restrict__ out)         // (A*B, S, H)
{
    // Pre-packed B fragments in LDS: B[k][n] = W[n][k], bf16.
    // Fragment (nt, ks): lane l holds B[32*ks + 8*(l>>4) + j][16*nt + (l&15)]
    __shared__ bf16x8 Bfrag[8][4][64];   // 32 KiB

    const int tid  = threadIdx.x;
    const int lane = tid & 63;
    const int wv   = tid >> 6;

    for (int e = tid; e < 8 * 4 * 64; e += 256) {
        int l  = e & 63;
        int ks = (e >> 6) & 3;
        int nt = e >> 8;
        int col = 16 * nt + (l & 15);      // n index (W row)
        int k0  = 32 * ks + 8 * (l >> 4);  // k index (W col)
        const float* wp = W + col * HN + k0;
        float4 w0 = *(const float4*)(wp);
        float4 w1 = *(const float4*)(wp + 4);
        bf16x8 f;
        f[0] = f2bf(w0.x); f[1] = f2bf(w0.y); f[2] = f2bf(w0.z); f[3] = f2bf(w0.w);
        f[4] = f2bf(w1.x); f[5] = f2bf(w1.y); f[6] = f2bf(w1.z); f[7] = f2bf(w1.w);
        Bfrag[nt][ks][l] = f;
    }
    __syncthreads();

    const int r  = lane & 15;  // A-row within strip / D-col within 16-tile
    const int kg = lane >> 4;  // k-group (A) / row-group (D)

    // bias per lane's output columns (col = 16*nt + r), strip-invariant
    float bcol[8];
#pragma unroll
    for (int nt = 0; nt < 8; ++nt) bcol[nt] = bias[16 * nt + r];

    for (int strip = blockIdx.x * 4 + wv; strip < NSTRIPS; strip += gridDim.x * 4) {
        const int ab = strip >> 6;            // 64 strips per (a,b)
        const int s0 = (strip & 63) << 4;
        const int a  = ab >> 6;
        const int b  = ab & 63;
        const int s_r = s0 + r;

        // alive scale for this lane's A-row: alive[a,b,s] / max(sum_a' alive, 1)
        int asum = 0, mya = 0;
#pragma unroll
        for (int a2 = 0; a2 < AN; ++a2) {
            int v = alive[(a2 * BN + b) * SN + s_r];
            asum += v;
            if (a2 == a) mya = v;
        }

        // rnn row -> bf16 fragments; DEAD ROWS SKIP THE LOADS ENTIRELY
        // (exec-masked: inactive lanes issue no memory requests -> ~50% of
        // rnn traffic eliminated). msg row = 0 for dead rows, matching ref.
        bf16x8 mb[4];
        if (mya) {
            const float scale = 1.0f / (float)(asum < 1 ? 1 : asum);
            const float* arow = rnn + ((size_t)s_r * BN + b) * (AN * HN) + a * HN;
#pragma unroll
            for (int ks = 0; ks < 4; ++ks) {
                const int k0 = 32 * ks + 8 * kg;
                float4 a0 = *(const float4*)(arow + k0);
                float4 a1 = *(const float4*)(arow + k0 + 4);
                mb[ks][0] = f2bf(a0.x * scale); mb[ks][1] = f2bf(a0.y * scale);
                mb[ks][2] = f2bf(a0.z * scale); mb[ks][3] = f2bf(a0.w * scale);
                mb[ks][4] = f2bf(a1.x * scale); mb[ks][5] = f2bf(a1.y * scale);
                mb[ks][6] = f2bf(a1.z * scale); mb[ks][7] = f2bf(a1.w * scale);
            }
        } else {
#pragma unroll
            for (int ks = 0; ks < 4; ++ks)
                mb[ks] = (bf16x8){0, 0, 0, 0, 0, 0, 0, 0};
        }

        f32x4 acc[8];
#pragma unroll
        for (int nt = 0; nt < 8; ++nt) acc[nt] = (f32x4){0.f, 0.f, 0.f, 0.f};
#pragma unroll
        for (int ks = 0; ks < 4; ++ks) {
#pragma unroll
            for (int nt = 0; nt < 8; ++nt)
                acc[nt] = __builtin_amdgcn_mfma_f32_16x16x32_bf16(
                    mb[ks], Bfrag[nt][ks][lane], acc[nt], 0, 0, 0);
        }

        // Epilogue: D[row][col], row = 4*kg + rg, col = 16*nt + r.
        // Nontemporal stores: out has no reuse -> don't evict L3 read data.
        const int outbase = ab * (SN * HN) + s0 * HN;
#pragma unroll
        for (int nt = 0; nt < 8; ++nt) {
            const int col = 16 * nt + r;
#pragma unroll
            for (int rg = 0; rg < 4; ++rg) {
                const int orow = 4 * kg + rg;
                const int idx = outbase + orow * HN + col;
                float v = acc[nt][rg] + bcol[nt] + obs[idx];
                __builtin_nontemporal_store(v, out + idx);
            }
        }
    }
}

extern "C" void kernel_launch(void* const* d_in, const int* in_sizes, int n_in,
                              void* d_out, int out_size, void* d_ws, size_t ws_size,
                              hipStream_t stream) {
    const float* obs   = (const float*)d_in[0];
    const float* rnn   = (const float*)d_in[1];
    const int*   alive = (const int*)d_in[2];
    const float* W     = (const float*)d_in[3];
    const float* bias  = (const float*)d_in[4];
    float* out = (float*)d_out;
    (void)in_sizes; (void)n_in; (void)d_ws; (void)ws_size; (void)out_size;

    commnet_fused<<<2048, 256, 0, stream>>>(obs, rnn, alive, W, bias, out);
}

// Round 9
// 135.844 us; speedup vs baseline: 1.3898x; 1.0758x over previous
//
#include <hip/hip_runtime.h>
#include <hip/hip_bf16.h>

// Problem constants: A=8 agents, B=64 envs, S=1024 seq, H=128 hidden.
#define AN 8
#define BN 64
#define SN 1024
#define HN 128
// rows M = A*B*S = 524288, strips of 16 rows = 32768 strips
#define NSTRIPS ((AN * BN * SN) / 16)
#define SP 132   // stripbuf row pitch (floats): 528B rows, 16B-aligned, bank-rotating

typedef __attribute__((ext_vector_type(8))) short bf16x8;
typedef __attribute__((ext_vector_type(4))) float f32x4;

__device__ __forceinline__ short f2bf(float f) {
    unsigned u = __builtin_bit_cast(unsigned, f);
    // round-to-nearest-even to bf16
    unsigned r = (u + 0x7fffu + ((u >> 16) & 1u)) >> 16;
    return (short)r;
}

__global__ __launch_bounds__(256) void commnet_fused(
    const float* __restrict__ obs,   // (A*B, S, H)
    const float* __restrict__ rnn,   // (S, B, A, H)
    const int*   __restrict__ alive, // (A, B, S, 1)
    const float* __restrict__ W,     // (H, H) [out, in]
    const float* __restrict__ bias,  // (H,)
    float* __restrict__ out)         // (A*B, S, H)
{
    // Pre-packed B fragments in LDS: B[k][n] = W[n][k], bf16.
    // Fragment (nt, ks): lane l holds B[32*ks + 8*(l>>4) + j][16*nt + (l&15)]
    __shared__ bf16x8 Bfrag[8][4][64];      // 32 KiB
    __shared__ float  stripbuf[4][16 * SP]; // 33 KiB: per-wave 16x128 out tile

    const int tid  = threadIdx.x;
    const int lane = tid & 63;
    const int wv   = tid >> 6;

    for (int e = tid; e < 8 * 4 * 64; e += 256) {
        int l  = e & 63;
        int ks = (e >> 6) & 3;
        int nt = e >> 8;
        int col = 16 * nt + (l & 15);      // n index (W row)
        int k0  = 32 * ks + 8 * (l >> 4);  // k index (W col)
        const float* wp = W + col * HN + k0;
        float4 w0 = *(const float4*)(wp);
        float4 w1 = *(const float4*)(wp + 4);
        bf16x8 f;
        f[0] = f2bf(w0.x); f[1] = f2bf(w0.y); f[2] = f2bf(w0.z); f[3] = f2bf(w0.w);
        f[4] = f2bf(w1.x); f[5] = f2bf(w1.y); f[6] = f2bf(w1.z); f[7] = f2bf(w1.w);
        Bfrag[nt][ks][l] = f;
    }
    __syncthreads();

    const int r  = lane & 15;  // A-row within strip / D-col within 16-tile
    const int kg = lane >> 4;  // k-group (A) / row-group (D)

    // Epilogue lane geometry: column block is loop-invariant.
    const int ecol = 4 * (lane & 31);          // 0..124
    const int erow = lane >> 5;                // 0/1 (row parity within pair)
    const float4 bv = *(const float4*)(bias + ecol);  // bias for lane's 4 cols

    for (int strip = blockIdx.x * 4 + wv; strip < NSTRIPS; strip += gridDim.x * 4) {
        const int ab = strip >> 6;            // 64 strips per (a,b)
        const int s0 = (strip & 63) << 4;
        const int a  = ab >> 6;
        const int b  = ab & 63;
        const int s_r = s0 + r;

        // alive scale for this lane's A-row: alive[a,b,s] / max(sum_a' alive, 1)
        int asum = 0, mya = 0;
#pragma unroll
        for (int a2 = 0; a2 < AN; ++a2) {
            int v = alive[(a2 * BN + b) * SN + s_r];
            asum += v;
            if (a2 == a) mya = v;
        }

        // rnn row -> bf16 fragments; DEAD ROWS SKIP THE LOADS ENTIRELY
        // (exec-masked: inactive lanes issue no requests -> ~50% of rnn
        // traffic eliminated). msg row = 0 for dead rows, matching ref.
        bf16x8 mb[4];
        if (mya) {
            const float scale = 1.0f / (float)(asum < 1 ? 1 : asum);
            const float* arow = rnn + ((size_t)s_r * BN + b) * (AN * HN) + a * HN;
#pragma unroll
            for (int ks = 0; ks < 4; ++ks) {
                const int k0 = 32 * ks + 8 * kg;
                float4 a0 = *(const float4*)(arow + k0);
                float4 a1 = *(const float4*)(arow + k0 + 4);
                mb[ks][0] = f2bf(a0.x * scale); mb[ks][1] = f2bf(a0.y * scale);
                mb[ks][2] = f2bf(a0.z * scale); mb[ks][3] = f2bf(a0.w * scale);
                mb[ks][4] = f2bf(a1.x * scale); mb[ks][5] = f2bf(a1.y * scale);
                mb[ks][6] = f2bf(a1.z * scale); mb[ks][7] = f2bf(a1.w * scale);
            }
        } else {
#pragma unroll
            for (int ks = 0; ks < 4; ++ks)
                mb[ks] = (bf16x8){0, 0, 0, 0, 0, 0, 0, 0};
        }

        f32x4 acc[8];
#pragma unroll
        for (int nt = 0; nt < 8; ++nt) acc[nt] = (f32x4){0.f, 0.f, 0.f, 0.f};
#pragma unroll
        for (int ks = 0; ks < 4; ++ks) {
#pragma unroll
            for (int nt = 0; nt < 8; ++nt)
                acc[nt] = __builtin_amdgcn_mfma_f32_16x16x32_bf16(
                    mb[ks], Bfrag[nt][ks][lane], acc[nt], 0, 0, 0);
        }

        // Stage result in per-wave LDS tile: D[row=4*kg+rg][col=16*nt+r].
        float* sb = stripbuf[wv];
#pragma unroll
        for (int nt = 0; nt < 8; ++nt) {
            const int col = 16 * nt + r;
#pragma unroll
            for (int rg = 0; rg < 4; ++rg)
                sb[(4 * kg + rg) * SP + col] = acc[nt][rg];
        }

        // Lane-linear read-back -> full-line NT stores (1KB contiguous per
        // instruction: two whole 512B output rows). obs read matches.
        const size_t outbase = (size_t)ab * (SN * HN) + (size_t)s0 * HN;
#pragma unroll
        for (int i = 0; i < 8; ++i) {
            const int row = 2 * i + erow;
            f32x4 v = *(const f32x4*)&sb[row * SP + ecol];
            const size_t idx = outbase + (size_t)row * HN + ecol;
            float4 o = *(const float4*)(obs + idx);
            float4 res;
            res.x = v[0] + bv.x + o.x;
            res.y = v[1] + bv.y + o.y;
            res.z = v[2] + bv.z + o.z;
            res.w = v[3] + bv.w + o.w;
            __builtin_nontemporal_store(res.x, out + idx);
            __builtin_nontemporal_store(res.y, out + idx + 1);
            __builtin_nontemporal_store(res.z, out + idx + 2);
            __builtin_nontemporal_store(res.w, out + idx + 3);
        }
    }
}

extern "C" void kernel_launch(void* const* d_in, const int* in_sizes, int n_in,
                              void* d_out, int out_size, void* d_ws, size_t ws_size,
                              hipStream_t stream) {
    const float* obs   = (const float*)d_in[0];
    const float* rnn   = (const float*)d_in[1];
    const int*   alive = (const int*)d_in[2];
    const float* W     = (const float*)d_in[3];
    const float* bias  = (const float*)d_in[4];
    float* out = (float*)d_out;
    (void)in_sizes; (void)n_in; (void)d_ws; (void)ws_size; (void)out_size;

    commnet_fused<<<2048, 256, 0, stream>>>(obs, rnn, alive, W, bias, out);
}